// Round 9
// baseline (633.825 us; speedup 1.0000x reference)
//
#include <hip/hip_runtime.h>
#include <hip/hip_bf16.h>

typedef __hip_bfloat16 bf16;
typedef unsigned short ushort;
typedef __attribute__((ext_vector_type(8))) short short8;  // 8 bf16 (4 VGPRs)
typedef __attribute__((ext_vector_type(4))) float f32x4;   // 4 fp32 acc

__device__ __forceinline__ float b2f(bf16 h) { return __bfloat162float(h); }
__device__ __forceinline__ bf16 f2b(float f) { return __float2bfloat16(f); }
__device__ __forceinline__ ushort f2bu(float f) {
    bf16 t = __float2bfloat16(f);
    ushort u;
    __builtin_memcpy(&u, &t, 2);
    return u;
}
__device__ __forceinline__ float bits2f(unsigned int u16) {
    unsigned int v = u16 << 16;
    float f;
    __builtin_memcpy(&f, &v, 4);
    return f;
}

// ---- dtype-generic helpers (proven skeleton) ------------------------------
template <typename T> __device__ __forceinline__ float toF(T v);
template <> __device__ __forceinline__ float toF<bf16>(bf16 v) { return b2f(v); }
template <> __device__ __forceinline__ float toF<float>(float v) { return v; }

template <typename T> __device__ __forceinline__ T fromF(float v);
template <> __device__ __forceinline__ bf16 fromF<bf16>(float v) { return f2b(v); }
template <> __device__ __forceinline__ float fromF<float>(float v) { return v; }

template <typename T> __device__ __forceinline__ void load8f(const T* p, float* f);
template <> __device__ __forceinline__ void load8f<bf16>(const bf16* p, float* f) {
    uint4 u = *(const uint4*)p;
    f[0] = bits2f(u.x & 0xffffu); f[1] = bits2f(u.x >> 16);
    f[2] = bits2f(u.y & 0xffffu); f[3] = bits2f(u.y >> 16);
    f[4] = bits2f(u.z & 0xffffu); f[5] = bits2f(u.z >> 16);
    f[6] = bits2f(u.w & 0xffffu); f[7] = bits2f(u.w >> 16);
}
template <> __device__ __forceinline__ void load8f<float>(const float* p, float* f) {
    float4 a = *(const float4*)p;
    float4 b = *(const float4*)(p + 4);
    f[0] = a.x; f[1] = a.y; f[2] = a.z; f[3] = a.w;
    f[4] = b.x; f[5] = b.y; f[6] = b.z; f[7] = b.w;
}

// load 16 consecutive T as 16 packed bf16 (two uint4)
template <typename T> __device__ __forceinline__ void load16b(const T* p, uint4& o0, uint4& o1);
template <> __device__ __forceinline__ void load16b<bf16>(const bf16* p, uint4& o0, uint4& o1) {
    o0 = *(const uint4*)p;
    o1 = *(const uint4*)(p + 8);
}
template <> __device__ __forceinline__ void load16b<float>(const float* p, uint4& o0, uint4& o1) {
    float f[16];
    load8f<float>(p, f);
    load8f<float>(p + 8, f + 8);
    unsigned int w[8];
    #pragma unroll
    for (int i = 0; i < 8; ++i)
        w[i] = (unsigned int)f2bu(f[2 * i]) | ((unsigned int)f2bu(f[2 * i + 1]) << 16);
    o0 = make_uint4(w[0], w[1], w[2], w[3]);
    o1 = make_uint4(w[4], w[5], w[6], w[7]);
}

// load 8 consecutive T as bf16 fragment scaled by s
template <typename T> __device__ __forceinline__ short8 frag8s(const T* p, float s) {
    float f[8];
    load8f<T>(p, f);
    short8 r;
    #pragma unroll
    for (int j = 0; j < 8; ++j) r[j] = (short)f2bu(f[j] * s);
    return r;
}

// ---- runtime dtype probe (proven) -----------------------------------------
__global__ void detect_dtype_kernel(const unsigned short* __restrict__ x,
                                    int* __restrict__ flag) {
    __shared__ int cnt;
    if (threadIdx.x == 0) cnt = 0;
    __syncthreads();
    int local = 0;
    for (int i = threadIdx.x; i < 2048; i += 256) {
        float v = bits2f((unsigned int)x[i]);
        if (!(fabsf(v) < 1e4f)) local++;
    }
    atomicAdd(&cnt, local);
    __syncthreads();
    if (threadIdx.x == 0) flag[0] = (cnt >= 8) ? 1 : 0;
}

// ================= MFMA GEMM, BK=64, register-prefetch pipeline =============
// C = act(A @ Bw^T + bias). 128x128 tile, 4 waves 2x2, wave = 4x4 of 16x16x32.
// A-frag m=lane&15,k=quad*8+j; C/D col=lane&15,row=quad*4+reg (m89-verified,
// empirically validated round 8).
template <typename T>
__device__ __forceinline__ void gemm_body(
    const T* __restrict__ A, const T* __restrict__ Bw,
    const T* __restrict__ bias, T* __restrict__ C,
    int N, int K, int bm, int bn, int relu)
{
    __shared__ ushort As[128][64];  // [m][k], 128 B rows (m97 layout)
    __shared__ ushort Bs[128][64];  // [n][k]
    const int tid = threadIdx.x;
    const int w = tid >> 6, lane = tid & 63;
    const int quad = lane >> 4, l15 = lane & 15;
    const int wr = (w >> 1) * 64, wc = (w & 1) * 64;

    const int sr = tid >> 1;        // staging row 0..127
    const int sc = (tid & 1) * 32;  // staging col base 0/32

    f32x4 acc[4][4];
    #pragma unroll
    for (int i = 0; i < 4; ++i)
        #pragma unroll
        for (int j = 0; j < 4; ++j) acc[i][j] = (f32x4){0.f, 0.f, 0.f, 0.f};

    const T* aP = A + (size_t)(bm + sr) * K + sc;
    const T* bP = Bw + (size_t)(bn + sr) * K + sc;

    uint4 ra[4], rb[4];
    load16b<T>(aP, ra[0], ra[1]);
    load16b<T>(aP + 16, ra[2], ra[3]);
    load16b<T>(bP, rb[0], rb[1]);
    load16b<T>(bP + 16, rb[2], rb[3]);

    for (int k0 = 0; k0 < K; k0 += 64) {
        __syncthreads();  // prior iteration's fragment reads complete
        *(uint4*)&As[sr][sc]      = ra[0];
        *(uint4*)&As[sr][sc + 8]  = ra[1];
        *(uint4*)&As[sr][sc + 16] = ra[2];
        *(uint4*)&As[sr][sc + 24] = ra[3];
        *(uint4*)&Bs[sr][sc]      = rb[0];
        *(uint4*)&Bs[sr][sc + 8]  = rb[1];
        *(uint4*)&Bs[sr][sc + 16] = rb[2];
        *(uint4*)&Bs[sr][sc + 24] = rb[3];
        __syncthreads();
        if (k0 + 64 < K) {  // prefetch next tile; latency hides behind MFMAs
            load16b<T>(aP + k0 + 64, ra[0], ra[1]);
            load16b<T>(aP + k0 + 80, ra[2], ra[3]);
            load16b<T>(bP + k0 + 64, rb[0], rb[1]);
            load16b<T>(bP + k0 + 80, rb[2], rb[3]);
        }
        #pragma unroll
        for (int kk = 0; kk < 2; ++kk) {
            short8 af[4], bfv[4];
            #pragma unroll
            for (int i = 0; i < 4; ++i) {
                af[i] = *(const short8*)&As[wr + i * 16 + l15][kk * 32 + quad * 8];
                bfv[i] = *(const short8*)&Bs[wc + i * 16 + l15][kk * 32 + quad * 8];
            }
            #pragma unroll
            for (int i = 0; i < 4; ++i)
                #pragma unroll
                for (int j = 0; j < 4; ++j)
                    acc[i][j] = __builtin_amdgcn_mfma_f32_16x16x32_bf16(
                        af[i], bfv[j], acc[i][j], 0, 0, 0);
        }
    }

    #pragma unroll
    for (int j = 0; j < 4; ++j) {
        int col = bn + wc + j * 16 + l15;
        float bv = toF<T>(bias[col]);
        #pragma unroll
        for (int i = 0; i < 4; ++i) {
            int row0 = bm + wr + i * 16 + quad * 4;
            #pragma unroll
            for (int r = 0; r < 4; ++r) {
                float vv = acc[i][j][r] + bv;
                if (relu) vv = fmaxf(vv, 0.f);
                C[(size_t)(row0 + r) * N + col] = fromF<T>(vv);
            }
        }
    }
}

template <typename T>
__global__ __launch_bounds__(256) void gemm_mfma(
    const int* __restrict__ dflag, int want,
    const T* __restrict__ A, const T* __restrict__ Bw,
    const T* __restrict__ bias, T* __restrict__ C,
    int N, int K, int relu)
{
    if (dflag[0] != want) return;
    gemm_body<T>(A, Bw, bias, C, N, K, blockIdx.y * 128, blockIdx.x * 128, relu);
}

template <typename T>
__global__ __launch_bounds__(256) void gemm_qkv(
    const int* __restrict__ dflag, int want, const T* __restrict__ x,
    const T* __restrict__ wq, const T* __restrict__ bq,
    const T* __restrict__ wk, const T* __restrict__ bk,
    const T* __restrict__ wv, const T* __restrict__ bv,
    T* __restrict__ qb, T* __restrict__ kb, T* __restrict__ vb)
{
    if (dflag[0] != want) return;
    const int mat = blockIdx.x / 6;
    const int bn = (blockIdx.x % 6) * 128;
    const T* W = (mat == 0) ? wq : (mat == 1) ? wk : wv;
    const T* Bi = (mat == 0) ? bq : (mat == 1) ? bk : bv;
    T* O = (mat == 0) ? qb : (mat == 1) ? kb : vb;
    gemm_body<T>(x, W, Bi, O, 768, 768, blockIdx.y * 128, bn, 0);
}

// ============== MFMA flash attention (64 q-rows/block) ======================
// Scale 1/8 folded into Q fragments (bf16-exact); additive mask bias;
// 2 barriers per k-tile (Ps is wave-private -> no mid barrier).
template <typename T>
__global__ __launch_bounds__(256) void attn_mfma(
    const int* __restrict__ dflag, int want,
    const T* __restrict__ q, const T* __restrict__ k,
    const T* __restrict__ v, const int* __restrict__ mask,
    T* __restrict__ ctx)
{
    if (dflag[0] != want) return;
    const int S = 2048, D = 768;
    __shared__ ushort Ks[64][72];      // [key][dim]
    __shared__ ushort Vt[64][72];      // [dim][key]
    __shared__ ushort Ps[4][16][72];   // per-wave P: [qrow][key]
    __shared__ float mk[64];           // additive bias: 0 or -1e9

    const int tid = threadIdx.x;
    const int w = tid >> 6, lane = tid & 63;
    const int quad = lane >> 4, l15 = lane & 15;

    const int bx = blockIdx.x;
    const int q0 = (bx & 31) * 64;
    const int h = (bx >> 5) % 12;
    const int b = bx / 384;

    // Q fragments pre-scaled by 0.125 (exact in bf16)
    const size_t qrow = (size_t)(b * S + q0 + w * 16 + l15) * D + h * 64;
    const short8 aQ0 = frag8s<T>(q + qrow + quad * 8, 0.125f);
    const short8 aQ1 = frag8s<T>(q + qrow + 32 + quad * 8, 0.125f);

    f32x4 o[4];
    float m_run[4], l_run[4];
    #pragma unroll
    for (int i = 0; i < 4; ++i) {
        o[i] = (f32x4){0.f, 0.f, 0.f, 0.f};
        m_run[i] = -3.0e38f;
        l_run[i] = 0.f;
    }

    const int sr = tid >> 2;          // staging key row 0..63
    const int sc0 = (tid & 3) * 16;   // staging dim base

    for (int k0 = 0; k0 < S; k0 += 64) {
        {
            const size_t krow = (size_t)(b * S + k0 + sr) * D + h * 64 + sc0;
            uint4 ka0, ka1, va0, va1;
            load16b<T>(k + krow, ka0, ka1);
            load16b<T>(v + krow, va0, va1);
            *(uint4*)&Ks[sr][sc0] = ka0;
            *(uint4*)&Ks[sr][sc0 + 8] = ka1;
            alignas(16) ushort tmp[16];
            *(uint4*)tmp = va0;
            *(uint4*)(tmp + 8) = va1;
            #pragma unroll
            for (int i = 0; i < 16; ++i) Vt[sc0 + i][sr] = tmp[i];
            if (tid < 64) mk[tid] = mask[b * S + k0 + tid] ? -1e9f : 0.f;
        }
        __syncthreads();

        // ---- QK^T + online softmax ----
        float p[4][4];
        {
            float scv[4][4];
            float vmax[4] = {-3e38f, -3e38f, -3e38f, -3e38f};
            #pragma unroll
            for (int s = 0; s < 4; ++s) {
                short8 bk0 = *(const short8*)&Ks[s * 16 + l15][quad * 8];
                short8 bk1 = *(const short8*)&Ks[s * 16 + l15][32 + quad * 8];
                f32x4 c = (f32x4){0.f, 0.f, 0.f, 0.f};
                c = __builtin_amdgcn_mfma_f32_16x16x32_bf16(aQ0, bk0, c, 0, 0, 0);
                c = __builtin_amdgcn_mfma_f32_16x16x32_bf16(aQ1, bk1, c, 0, 0, 0);
                float mbias = mk[s * 16 + l15];
                #pragma unroll
                for (int r = 0; r < 4; ++r) {
                    float val = c[r] + mbias;   // scale folded into Q
                    scv[s][r] = val;
                    vmax[r] = fmaxf(vmax[r], val);
                }
            }
            #pragma unroll
            for (int r = 0; r < 4; ++r) {
                float vm = vmax[r];
                vm = fmaxf(vm, __shfl_xor(vm, 1, 16));
                vm = fmaxf(vm, __shfl_xor(vm, 2, 16));
                vm = fmaxf(vm, __shfl_xor(vm, 4, 16));
                vm = fmaxf(vm, __shfl_xor(vm, 8, 16));
                float mn = fmaxf(m_run[r], vm);
                float alpha = __expf(m_run[r] - mn);
                m_run[r] = mn;
                l_run[r] *= alpha;
                #pragma unroll
                for (int s = 0; s < 4; ++s) o[s][r] *= alpha;
                float rs = 0.f;
                #pragma unroll
                for (int s = 0; s < 4; ++s) {
                    p[s][r] = __expf(scv[s][r] - mn);
                    rs += p[s][r];
                }
                rs += __shfl_xor(rs, 1, 16);
                rs += __shfl_xor(rs, 2, 16);
                rs += __shfl_xor(rs, 4, 16);
                rs += __shfl_xor(rs, 8, 16);
                l_run[r] += rs;
            }
        }
        // P: C-layout -> wave-private LDS -> A-layout (no barrier needed)
        #pragma unroll
        for (int r = 0; r < 4; ++r)
            #pragma unroll
            for (int s = 0; s < 4; ++s)
                Ps[w][quad * 4 + r][s * 16 + l15] = f2bu(p[s][r]);

        // ---- PV ----
        {
            short8 aP0 = *(const short8*)&Ps[w][l15][quad * 8];
            short8 aP1 = *(const short8*)&Ps[w][l15][32 + quad * 8];
            #pragma unroll
            for (int s = 0; s < 4; ++s) {
                short8 bv0 = *(const short8*)&Vt[s * 16 + l15][quad * 8];
                short8 bv1 = *(const short8*)&Vt[s * 16 + l15][32 + quad * 8];
                o[s] = __builtin_amdgcn_mfma_f32_16x16x32_bf16(aP0, bv0, o[s], 0, 0, 0);
                o[s] = __builtin_amdgcn_mfma_f32_16x16x32_bf16(aP1, bv1, o[s], 0, 0, 0);
            }
        }
        __syncthreads();  // Ks/Vt reads done before next staging
    }

    const size_t obase = (size_t)(b * S + q0 + w * 16) * D + h * 64;
    #pragma unroll
    for (int r = 0; r < 4; ++r) {
        float inv = 1.f / l_run[r];
        #pragma unroll
        for (int s = 0; s < 4; ++s)
            ctx[obase + (size_t)(quad * 4 + r) * D + s * 16 + l15] =
                fromF<T>(o[s][r] * inv);
    }
}

// ---- residual + LayerNorm (proven) ----------------------------------------
template <typename T>
__global__ __launch_bounds__(256) void ln_res_kernel(
    const int* __restrict__ dflag, int want,
    const T* __restrict__ a, const T* __restrict__ r,
    const T* __restrict__ gamma, const T* __restrict__ beta,
    T* __restrict__ out)
{
    if (dflag[0] != want) return;
    const int D = 768;
    const int row = blockIdx.x;
    const int tid = threadIdx.x;
    __shared__ float red[4];
    const size_t base = (size_t)row * D;

    float x[3];
    #pragma unroll
    for (int i = 0; i < 3; ++i) {
        int d = tid + i * 256;
        x[i] = toF<T>(a[base + d]) + toF<T>(r[base + d]);
    }

    float s = x[0] + x[1] + x[2];
    #pragma unroll
    for (int off = 32; off > 0; off >>= 1) s += __shfl_down(s, off, 64);
    if ((tid & 63) == 0) red[tid >> 6] = s;
    __syncthreads();
    float mean = (red[0] + red[1] + red[2] + red[3]) * (1.f / 768.f);
    __syncthreads();

    float vsum = 0.f;
    #pragma unroll
    for (int i = 0; i < 3; ++i) {
        float dd = x[i] - mean;
        vsum += dd * dd;
    }
    #pragma unroll
    for (int off = 32; off > 0; off >>= 1) vsum += __shfl_down(vsum, off, 64);
    if ((tid & 63) == 0) red[tid >> 6] = vsum;
    __syncthreads();
    float var = (red[0] + red[1] + red[2] + red[3]) * (1.f / 767.f);
    float inv = 1.f / (sqrtf(var) + 1e-6f);

    #pragma unroll
    for (int i = 0; i < 3; ++i) {
        int d = tid + i * 256;
        out[base + d] = fromF<T>(toF<T>(gamma[d]) * (x[i] - mean) * inv + toF<T>(beta[d]));
    }
}

// ---- full pipeline for element type T --------------------------------------
template <typename T>
static void launch_pipeline(void* const* d_in, void* d_out, char* buf,
                            const int* dflag, int want, hipStream_t stream)
{
    const int Bb = 2, S = 2048, D = 768, DFF = 3072;
    const int M = Bb * S;

    const T* x    = (const T*)d_in[0];
    const int* mask = (const int*)d_in[1];
    const T* wq = (const T*)d_in[2];
    const T* bq = (const T*)d_in[3];
    const T* wk = (const T*)d_in[4];
    const T* bk = (const T*)d_in[5];
    const T* wv = (const T*)d_in[6];
    const T* bv = (const T*)d_in[7];
    const T* wo = (const T*)d_in[8];
    const T* bo = (const T*)d_in[9];
    const T* w1 = (const T*)d_in[10];
    const T* b1 = (const T*)d_in[11];
    const T* w2 = (const T*)d_in[12];
    const T* b2 = (const T*)d_in[13];
    const T* g1  = (const T*)d_in[14];
    const T* be1 = (const T*)d_in[15];
    const T* g2  = (const T*)d_in[16];
    const T* be2 = (const T*)d_in[17];

    T* out = (T*)d_out;
    T* ws = (T*)buf;

    const size_t nxd = (size_t)M * D;
    const size_t nff = (size_t)M * DFF;

    T* qb    = ws;
    T* kb    = ws + nxd;
    T* vb    = ws + 2 * nxd;
    T* ctx   = ws + nff;
    T* oproj = ws + nff + nxd;
    T* ln1   = ws + nff + 2 * nxd;
    T* ff1   = ws;     // reuse q/k/v region
    T* ff2   = ctx;    // reuse ctx

    dim3 blk(256);
    gemm_qkv<T><<<dim3(18, 32), blk, 0, stream>>>(dflag, want, x, wq, bq, wk, bk, wv, bv, qb, kb, vb);
    attn_mfma<T><<<dim3(768), blk, 0, stream>>>(dflag, want, qb, kb, vb, mask, ctx);
    gemm_mfma<T><<<dim3(6, 32), blk, 0, stream>>>(dflag, want, ctx, wo, bo, oproj, D, D, 0);
    ln_res_kernel<T><<<dim3(M), blk, 0, stream>>>(dflag, want, x, oproj, g1, be1, ln1);
    gemm_mfma<T><<<dim3(24, 32), blk, 0, stream>>>(dflag, want, ln1, w1, b1, ff1, DFF, D, 1);
    gemm_mfma<T><<<dim3(6, 32), blk, 0, stream>>>(dflag, want, ff1, w2, b2, ff2, D, DFF, 0);
    ln_res_kernel<T><<<dim3(M), blk, 0, stream>>>(dflag, want, ln1, ff2, g2, be2, out);
}

extern "C" void kernel_launch(void* const* d_in, const int* in_sizes, int n_in,
                              void* d_out, int out_size, void* d_ws, size_t ws_size,
                              hipStream_t stream) {
    char* base = (char*)d_ws;
    int* dflag = (int*)base;
    char* buf = base + 256;

    detect_dtype_kernel<<<dim3(1), dim3(256), 0, stream>>>(
        (const unsigned short*)d_in[0], dflag);

    launch_pipeline<bf16>(d_in, d_out, buf, dflag, 0, stream);
    launch_pipeline<float>(d_in, d_out, buf, dflag, 1, stream);
}

// Round 10
// 612.474 us; speedup vs baseline: 1.0349x; 1.0349x over previous
//
#include <hip/hip_runtime.h>
#include <hip/hip_bf16.h>

typedef __hip_bfloat16 bf16;
typedef unsigned short ushort;
typedef __attribute__((ext_vector_type(8))) short short8;  // 8 bf16 (4 VGPRs)
typedef __attribute__((ext_vector_type(4))) float f32x4;   // 4 fp32 acc

__device__ __forceinline__ float b2f(bf16 h) { return __bfloat162float(h); }
__device__ __forceinline__ bf16 f2b(float f) { return __float2bfloat16(f); }
__device__ __forceinline__ ushort f2bu(float f) {
    bf16 t = __float2bfloat16(f);
    ushort u;
    __builtin_memcpy(&u, &t, 2);
    return u;
}
__device__ __forceinline__ float bits2f(unsigned int u16) {
    unsigned int v = u16 << 16;
    float f;
    __builtin_memcpy(&f, &v, 4);
    return f;
}

// ---- dtype-generic helpers (proven skeleton) ------------------------------
template <typename T> __device__ __forceinline__ float toF(T v);
template <> __device__ __forceinline__ float toF<bf16>(bf16 v) { return b2f(v); }
template <> __device__ __forceinline__ float toF<float>(float v) { return v; }

template <typename T> __device__ __forceinline__ T fromF(float v);
template <> __device__ __forceinline__ bf16 fromF<bf16>(float v) { return f2b(v); }
template <> __device__ __forceinline__ float fromF<float>(float v) { return v; }

template <typename T> __device__ __forceinline__ void load8f(const T* p, float* f);
template <> __device__ __forceinline__ void load8f<bf16>(const bf16* p, float* f) {
    uint4 u = *(const uint4*)p;
    f[0] = bits2f(u.x & 0xffffu); f[1] = bits2f(u.x >> 16);
    f[2] = bits2f(u.y & 0xffffu); f[3] = bits2f(u.y >> 16);
    f[4] = bits2f(u.z & 0xffffu); f[5] = bits2f(u.z >> 16);
    f[6] = bits2f(u.w & 0xffffu); f[7] = bits2f(u.w >> 16);
}
template <> __device__ __forceinline__ void load8f<float>(const float* p, float* f) {
    float4 a = *(const float4*)p;
    float4 b = *(const float4*)(p + 4);
    f[0] = a.x; f[1] = a.y; f[2] = a.z; f[3] = a.w;
    f[4] = b.x; f[5] = b.y; f[6] = b.z; f[7] = b.w;
}

// load 16 consecutive T as 16 packed bf16 (two uint4)
template <typename T> __device__ __forceinline__ void load16b(const T* p, uint4& o0, uint4& o1);
template <> __device__ __forceinline__ void load16b<bf16>(const bf16* p, uint4& o0, uint4& o1) {
    o0 = *(const uint4*)p;
    o1 = *(const uint4*)(p + 8);
}
template <> __device__ __forceinline__ void load16b<float>(const float* p, uint4& o0, uint4& o1) {
    float f[16];
    load8f<float>(p, f);
    load8f<float>(p + 8, f + 8);
    unsigned int w[8];
    #pragma unroll
    for (int i = 0; i < 8; ++i)
        w[i] = (unsigned int)f2bu(f[2 * i]) | ((unsigned int)f2bu(f[2 * i + 1]) << 16);
    o0 = make_uint4(w[0], w[1], w[2], w[3]);
    o1 = make_uint4(w[4], w[5], w[6], w[7]);
}

// load 8 consecutive T as bf16 fragment scaled by s
template <typename T> __device__ __forceinline__ short8 frag8s(const T* p, float s) {
    float f[8];
    load8f<T>(p, f);
    short8 r;
    #pragma unroll
    for (int j = 0; j < 8; ++j) r[j] = (short)f2bu(f[j] * s);
    return r;
}

// ---- runtime dtype probe (proven) -----------------------------------------
__global__ void detect_dtype_kernel(const unsigned short* __restrict__ x,
                                    int* __restrict__ flag) {
    __shared__ int cnt;
    if (threadIdx.x == 0) cnt = 0;
    __syncthreads();
    int local = 0;
    for (int i = threadIdx.x; i < 2048; i += 256) {
        float v = bits2f((unsigned int)x[i]);
        if (!(fabsf(v) < 1e4f)) local++;
    }
    atomicAdd(&cnt, local);
    __syncthreads();
    if (threadIdx.x == 0) flag[0] = (cnt >= 8) ? 1 : 0;
}

// ========== MFMA GEMM, BK=64, reg-prefetch, CONFLICT-FREE LDS ==============
// C = act(A @ Bw^T + bias). 128x128 tile, 4 waves 2x2, wave = 4x4 of 16x16x32.
// LDS rows padded to 72 ushorts = 144 B: fragment-read bank start =
// (l15*36)%32 = l15*4%32 -> 2 lanes per 4-bank span -> 2-way (free, m136).
// 144 = 9*16 keeps every staged uint4 16B-aligned.
template <typename T>
__device__ __forceinline__ void gemm_body(
    const T* __restrict__ A, const T* __restrict__ Bw,
    const T* __restrict__ bias, T* __restrict__ C,
    int N, int K, int bm, int bn, int relu)
{
    __shared__ ushort As[128][72];  // [m][k], padded
    __shared__ ushort Bs[128][72];  // [n][k], padded
    const int tid = threadIdx.x;
    const int w = tid >> 6, lane = tid & 63;
    const int quad = lane >> 4, l15 = lane & 15;
    const int wr = (w >> 1) * 64, wc = (w & 1) * 64;

    const int sr = tid >> 1;        // staging row 0..127
    const int sc = (tid & 1) * 32;  // staging col base 0/32

    f32x4 acc[4][4];
    #pragma unroll
    for (int i = 0; i < 4; ++i)
        #pragma unroll
        for (int j = 0; j < 4; ++j) acc[i][j] = (f32x4){0.f, 0.f, 0.f, 0.f};

    const T* aP = A + (size_t)(bm + sr) * K + sc;
    const T* bP = Bw + (size_t)(bn + sr) * K + sc;

    uint4 ra[4], rb[4];
    load16b<T>(aP, ra[0], ra[1]);
    load16b<T>(aP + 16, ra[2], ra[3]);
    load16b<T>(bP, rb[0], rb[1]);
    load16b<T>(bP + 16, rb[2], rb[3]);

    for (int k0 = 0; k0 < K; k0 += 64) {
        __syncthreads();  // prior iteration's fragment reads complete
        *(uint4*)&As[sr][sc]      = ra[0];
        *(uint4*)&As[sr][sc + 8]  = ra[1];
        *(uint4*)&As[sr][sc + 16] = ra[2];
        *(uint4*)&As[sr][sc + 24] = ra[3];
        *(uint4*)&Bs[sr][sc]      = rb[0];
        *(uint4*)&Bs[sr][sc + 8]  = rb[1];
        *(uint4*)&Bs[sr][sc + 16] = rb[2];
        *(uint4*)&Bs[sr][sc + 24] = rb[3];
        __syncthreads();
        if (k0 + 64 < K) {  // prefetch next tile; hides behind 32 MFMAs
            load16b<T>(aP + k0 + 64, ra[0], ra[1]);
            load16b<T>(aP + k0 + 80, ra[2], ra[3]);
            load16b<T>(bP + k0 + 64, rb[0], rb[1]);
            load16b<T>(bP + k0 + 80, rb[2], rb[3]);
        }
        #pragma unroll
        for (int kk = 0; kk < 2; ++kk) {
            short8 af[4], bfv[4];
            #pragma unroll
            for (int i = 0; i < 4; ++i) {
                af[i] = *(const short8*)&As[wr + i * 16 + l15][kk * 32 + quad * 8];
                bfv[i] = *(const short8*)&Bs[wc + i * 16 + l15][kk * 32 + quad * 8];
            }
            #pragma unroll
            for (int i = 0; i < 4; ++i)
                #pragma unroll
                for (int j = 0; j < 4; ++j)
                    acc[i][j] = __builtin_amdgcn_mfma_f32_16x16x32_bf16(
                        af[i], bfv[j], acc[i][j], 0, 0, 0);
        }
    }

    #pragma unroll
    for (int j = 0; j < 4; ++j) {
        int col = bn + wc + j * 16 + l15;
        float bv = toF<T>(bias[col]);
        #pragma unroll
        for (int i = 0; i < 4; ++i) {
            int row0 = bm + wr + i * 16 + quad * 4;
            #pragma unroll
            for (int r = 0; r < 4; ++r) {
                float vv = acc[i][j][r] + bv;
                if (relu) vv = fmaxf(vv, 0.f);
                C[(size_t)(row0 + r) * N + col] = fromF<T>(vv);
            }
        }
    }
}

template <typename T>
__global__ __launch_bounds__(256) void gemm_mfma(
    const int* __restrict__ dflag, int want,
    const T* __restrict__ A, const T* __restrict__ Bw,
    const T* __restrict__ bias, T* __restrict__ C,
    int N, int K, int relu)
{
    if (dflag[0] != want) return;
    gemm_body<T>(A, Bw, bias, C, N, K, blockIdx.y * 128, blockIdx.x * 128, relu);
}

template <typename T>
__global__ __launch_bounds__(256) void gemm_qkv(
    const int* __restrict__ dflag, int want, const T* __restrict__ x,
    const T* __restrict__ wq, const T* __restrict__ bq,
    const T* __restrict__ wk, const T* __restrict__ bk,
    const T* __restrict__ wv, const T* __restrict__ bv,
    T* __restrict__ qb, T* __restrict__ kb, T* __restrict__ vb)
{
    if (dflag[0] != want) return;
    const int mat = blockIdx.x / 6;
    const int bn = (blockIdx.x % 6) * 128;
    const T* W = (mat == 0) ? wq : (mat == 1) ? wk : wv;
    const T* Bi = (mat == 0) ? bq : (mat == 1) ? bk : bv;
    T* O = (mat == 0) ? qb : (mat == 1) ? kb : vb;
    gemm_body<T>(x, W, Bi, O, 768, 768, blockIdx.y * 128, bn, 0);
}

// ============== MFMA flash attention (proven round-8/9 structure) ===========
template <typename T>
__global__ __launch_bounds__(256) void attn_mfma(
    const int* __restrict__ dflag, int want,
    const T* __restrict__ q, const T* __restrict__ k,
    const T* __restrict__ v, const int* __restrict__ mask,
    T* __restrict__ ctx)
{
    if (dflag[0] != want) return;
    const int S = 2048, D = 768;
    __shared__ ushort Ks[64][72];      // [key][dim]
    __shared__ ushort Vt[64][72];      // [dim][key]
    __shared__ ushort Ps[4][16][72];   // per-wave P: [qrow][key]
    __shared__ float mk[64];           // additive bias: 0 or -1e9

    const int tid = threadIdx.x;
    const int w = tid >> 6, lane = tid & 63;
    const int quad = lane >> 4, l15 = lane & 15;

    const int bx = blockIdx.x;
    const int q0 = (bx & 31) * 64;
    const int h = (bx >> 5) % 12;
    const int b = bx / 384;

    const size_t qrow = (size_t)(b * S + q0 + w * 16 + l15) * D + h * 64;
    const short8 aQ0 = frag8s<T>(q + qrow + quad * 8, 0.125f);
    const short8 aQ1 = frag8s<T>(q + qrow + 32 + quad * 8, 0.125f);

    f32x4 o[4];
    float m_run[4], l_run[4];
    #pragma unroll
    for (int i = 0; i < 4; ++i) {
        o[i] = (f32x4){0.f, 0.f, 0.f, 0.f};
        m_run[i] = -3.0e38f;
        l_run[i] = 0.f;
    }

    const int sr = tid >> 2;          // staging key row 0..63
    const int sc0 = (tid & 3) * 16;   // staging dim base

    for (int k0 = 0; k0 < S; k0 += 64) {
        {
            const size_t krow = (size_t)(b * S + k0 + sr) * D + h * 64 + sc0;
            uint4 ka0, ka1, va0, va1;
            load16b<T>(k + krow, ka0, ka1);
            load16b<T>(v + krow, va0, va1);
            *(uint4*)&Ks[sr][sc0] = ka0;
            *(uint4*)&Ks[sr][sc0 + 8] = ka1;
            alignas(16) ushort tmp[16];
            *(uint4*)tmp = va0;
            *(uint4*)(tmp + 8) = va1;
            #pragma unroll
            for (int i = 0; i < 16; ++i) Vt[sc0 + i][sr] = tmp[i];
            if (tid < 64) mk[tid] = mask[b * S + k0 + tid] ? -1e9f : 0.f;
        }
        __syncthreads();

        float p[4][4];
        {
            float scv[4][4];
            float vmax[4] = {-3e38f, -3e38f, -3e38f, -3e38f};
            #pragma unroll
            for (int s = 0; s < 4; ++s) {
                short8 bk0 = *(const short8*)&Ks[s * 16 + l15][quad * 8];
                short8 bk1 = *(const short8*)&Ks[s * 16 + l15][32 + quad * 8];
                f32x4 c = (f32x4){0.f, 0.f, 0.f, 0.f};
                c = __builtin_amdgcn_mfma_f32_16x16x32_bf16(aQ0, bk0, c, 0, 0, 0);
                c = __builtin_amdgcn_mfma_f32_16x16x32_bf16(aQ1, bk1, c, 0, 0, 0);
                float mbias = mk[s * 16 + l15];
                #pragma unroll
                for (int r = 0; r < 4; ++r) {
                    float val = c[r] + mbias;
                    scv[s][r] = val;
                    vmax[r] = fmaxf(vmax[r], val);
                }
            }
            #pragma unroll
            for (int r = 0; r < 4; ++r) {
                float vm = vmax[r];
                vm = fmaxf(vm, __shfl_xor(vm, 1, 16));
                vm = fmaxf(vm, __shfl_xor(vm, 2, 16));
                vm = fmaxf(vm, __shfl_xor(vm, 4, 16));
                vm = fmaxf(vm, __shfl_xor(vm, 8, 16));
                float mn = fmaxf(m_run[r], vm);
                float alpha = __expf(m_run[r] - mn);
                m_run[r] = mn;
                l_run[r] *= alpha;
                #pragma unroll
                for (int s = 0; s < 4; ++s) o[s][r] *= alpha;
                float rs = 0.f;
                #pragma unroll
                for (int s = 0; s < 4; ++s) {
                    p[s][r] = __expf(scv[s][r] - mn);
                    rs += p[s][r];
                }
                rs += __shfl_xor(rs, 1, 16);
                rs += __shfl_xor(rs, 2, 16);
                rs += __shfl_xor(rs, 4, 16);
                rs += __shfl_xor(rs, 8, 16);
                l_run[r] += rs;
            }
        }
        #pragma unroll
        for (int r = 0; r < 4; ++r)
            #pragma unroll
            for (int s = 0; s < 4; ++s)
                Ps[w][quad * 4 + r][s * 16 + l15] = f2bu(p[s][r]);

        {
            short8 aP0 = *(const short8*)&Ps[w][l15][quad * 8];
            short8 aP1 = *(const short8*)&Ps[w][l15][32 + quad * 8];
            #pragma unroll
            for (int s = 0; s < 4; ++s) {
                short8 bv0 = *(const short8*)&Vt[s * 16 + l15][quad * 8];
                short8 bv1 = *(const short8*)&Vt[s * 16 + l15][32 + quad * 8];
                o[s] = __builtin_amdgcn_mfma_f32_16x16x32_bf16(aP0, bv0, o[s], 0, 0, 0);
                o[s] = __builtin_amdgcn_mfma_f32_16x16x32_bf16(aP1, bv1, o[s], 0, 0, 0);
            }
        }
        __syncthreads();
    }

    const size_t obase = (size_t)(b * S + q0 + w * 16) * D + h * 64;
    #pragma unroll
    for (int r = 0; r < 4; ++r) {
        float inv = 1.f / l_run[r];
        #pragma unroll
        for (int s = 0; s < 4; ++s)
            ctx[obase + (size_t)(quad * 4 + r) * D + s * 16 + l15] =
                fromF<T>(o[s][r] * inv);
    }
}

// ---- residual + LayerNorm (proven) ----------------------------------------
template <typename T>
__global__ __launch_bounds__(256) void ln_res_kernel(
    const int* __restrict__ dflag, int want,
    const T* __restrict__ a, const T* __restrict__ r,
    const T* __restrict__ gamma, const T* __restrict__ beta,
    T* __restrict__ out)
{
    if (dflag[0] != want) return;
    const int D = 768;
    const int row = blockIdx.x;
    const int tid = threadIdx.x;
    __shared__ float red[4];
    const size_t base = (size_t)row * D;

    float x[3];
    #pragma unroll
    for (int i = 0; i < 3; ++i) {
        int d = tid + i * 256;
        x[i] = toF<T>(a[base + d]) + toF<T>(r[base + d]);
    }

    float s = x[0] + x[1] + x[2];
    #pragma unroll
    for (int off = 32; off > 0; off >>= 1) s += __shfl_down(s, off, 64);
    if ((tid & 63) == 0) red[tid >> 6] = s;
    __syncthreads();
    float mean = (red[0] + red[1] + red[2] + red[3]) * (1.f / 768.f);
    __syncthreads();

    float vsum = 0.f;
    #pragma unroll
    for (int i = 0; i < 3; ++i) {
        float dd = x[i] - mean;
        vsum += dd * dd;
    }
    #pragma unroll
    for (int off = 32; off > 0; off >>= 1) vsum += __shfl_down(vsum, off, 64);
    if ((tid & 63) == 0) red[tid >> 6] = vsum;
    __syncthreads();
    float var = (red[0] + red[1] + red[2] + red[3]) * (1.f / 767.f);
    float inv = 1.f / (sqrtf(var) + 1e-6f);

    #pragma unroll
    for (int i = 0; i < 3; ++i) {
        int d = tid + i * 256;
        out[base + d] = fromF<T>(toF<T>(gamma[d]) * (x[i] - mean) * inv + toF<T>(beta[d]));
    }
}

// ---- full pipeline for element type T --------------------------------------
template <typename T>
static void launch_pipeline(void* const* d_in, void* d_out, char* buf,
                            const int* dflag, int want, hipStream_t stream)
{
    const int Bb = 2, S = 2048, D = 768, DFF = 3072;
    const int M = Bb * S;

    const T* x    = (const T*)d_in[0];
    const int* mask = (const int*)d_in[1];
    const T* wq = (const T*)d_in[2];
    const T* bq = (const T*)d_in[3];
    const T* wk = (const T*)d_in[4];
    const T* bk = (const T*)d_in[5];
    const T* wv = (const T*)d_in[6];
    const T* bv = (const T*)d_in[7];
    const T* wo = (const T*)d_in[8];
    const T* bo = (const T*)d_in[9];
    const T* w1 = (const T*)d_in[10];
    const T* b1 = (const T*)d_in[11];
    const T* w2 = (const T*)d_in[12];
    const T* b2 = (const T*)d_in[13];
    const T* g1  = (const T*)d_in[14];
    const T* be1 = (const T*)d_in[15];
    const T* g2  = (const T*)d_in[16];
    const T* be2 = (const T*)d_in[17];

    T* out = (T*)d_out;
    T* ws = (T*)buf;

    const size_t nxd = (size_t)M * D;
    const size_t nff = (size_t)M * DFF;

    T* qb    = ws;
    T* kb    = ws + nxd;
    T* vb    = ws + 2 * nxd;
    T* ctx   = ws + nff;
    T* oproj = ws + nff + nxd;
    T* ln1   = ws + nff + 2 * nxd;
    T* ff1   = ws;     // reuse q/k/v region
    T* ff2   = ctx;    // reuse ctx

    dim3 blk(256);
    gemm_qkv<T><<<dim3(18, 32), blk, 0, stream>>>(dflag, want, x, wq, bq, wk, bk, wv, bv, qb, kb, vb);
    attn_mfma<T><<<dim3(768), blk, 0, stream>>>(dflag, want, qb, kb, vb, mask, ctx);
    gemm_mfma<T><<<dim3(6, 32), blk, 0, stream>>>(dflag, want, ctx, wo, bo, oproj, D, D, 0);
    ln_res_kernel<T><<<dim3(M), blk, 0, stream>>>(dflag, want, x, oproj, g1, be1, ln1);
    gemm_mfma<T><<<dim3(24, 32), blk, 0, stream>>>(dflag, want, ln1, w1, b1, ff1, DFF, D, 1);
    gemm_mfma<T><<<dim3(6, 32), blk, 0, stream>>>(dflag, want, ff1, w2, b2, ff2, D, DFF, 0);
    ln_res_kernel<T><<<dim3(M), blk, 0, stream>>>(dflag, want, ln1, ff2, g2, be2, out);
}

extern "C" void kernel_launch(void* const* d_in, const int* in_sizes, int n_in,
                              void* d_out, int out_size, void* d_ws, size_t ws_size,
                              hipStream_t stream) {
    char* base = (char*)d_ws;
    int* dflag = (int*)base;
    char* buf = base + 256;

    detect_dtype_kernel<<<dim3(1), dim3(256), 0, stream>>>(
        (const unsigned short*)d_in[0], dflag);

    launch_pipeline<bf16>(d_in, d_out, buf, dflag, 0, stream);
    launch_pipeline<float>(d_in, d_out, buf, dflag, 1, stream);
}

// Round 11
// 589.099 us; speedup vs baseline: 1.0759x; 1.0397x over previous
//
#include <hip/hip_runtime.h>
#include <hip/hip_bf16.h>

typedef __hip_bfloat16 bf16;
typedef unsigned short ushort;
typedef __attribute__((ext_vector_type(8))) short short8;  // 8 bf16 (4 VGPRs)
typedef __attribute__((ext_vector_type(4))) float f32x4;   // 4 fp32 acc

__device__ __forceinline__ float b2f(bf16 h) { return __bfloat162float(h); }
__device__ __forceinline__ bf16 f2b(float f) { return __float2bfloat16(f); }
__device__ __forceinline__ ushort f2bu(float f) {
    bf16 t = __float2bfloat16(f);
    ushort u;
    __builtin_memcpy(&u, &t, 2);
    return u;
}
__device__ __forceinline__ float bits2f(unsigned int u16) {
    unsigned int v = u16 << 16;
    float f;
    __builtin_memcpy(&f, &v, 4);
    return f;
}

// ---- dtype-generic helpers (proven skeleton) ------------------------------
template <typename T> __device__ __forceinline__ float toF(T v);
template <> __device__ __forceinline__ float toF<bf16>(bf16 v) { return b2f(v); }
template <> __device__ __forceinline__ float toF<float>(float v) { return v; }

template <typename T> __device__ __forceinline__ T fromF(float v);
template <> __device__ __forceinline__ bf16 fromF<bf16>(float v) { return f2b(v); }
template <> __device__ __forceinline__ float fromF<float>(float v) { return v; }

template <typename T> __device__ __forceinline__ void load8f(const T* p, float* f);
template <> __device__ __forceinline__ void load8f<bf16>(const bf16* p, float* f) {
    uint4 u = *(const uint4*)p;
    f[0] = bits2f(u.x & 0xffffu); f[1] = bits2f(u.x >> 16);
    f[2] = bits2f(u.y & 0xffffu); f[3] = bits2f(u.y >> 16);
    f[4] = bits2f(u.z & 0xffffu); f[5] = bits2f(u.z >> 16);
    f[6] = bits2f(u.w & 0xffffu); f[7] = bits2f(u.w >> 16);
}
template <> __device__ __forceinline__ void load8f<float>(const float* p, float* f) {
    float4 a = *(const float4*)p;
    float4 b = *(const float4*)(p + 4);
    f[0] = a.x; f[1] = a.y; f[2] = a.z; f[3] = a.w;
    f[4] = b.x; f[5] = b.y; f[6] = b.z; f[7] = b.w;
}

// load 16 consecutive T as 16 packed bf16 (two uint4)
template <typename T> __device__ __forceinline__ void load16b(const T* p, uint4& o0, uint4& o1);
template <> __device__ __forceinline__ void load16b<bf16>(const bf16* p, uint4& o0, uint4& o1) {
    o0 = *(const uint4*)p;
    o1 = *(const uint4*)(p + 8);
}
template <> __device__ __forceinline__ void load16b<float>(const float* p, uint4& o0, uint4& o1) {
    float f[16];
    load8f<float>(p, f);
    load8f<float>(p + 8, f + 8);
    unsigned int w[8];
    #pragma unroll
    for (int i = 0; i < 8; ++i)
        w[i] = (unsigned int)f2bu(f[2 * i]) | ((unsigned int)f2bu(f[2 * i + 1]) << 16);
    o0 = make_uint4(w[0], w[1], w[2], w[3]);
    o1 = make_uint4(w[4], w[5], w[6], w[7]);
}

// load 8 consecutive T as bf16 fragment scaled by s
template <typename T> __device__ __forceinline__ short8 frag8s(const T* p, float s) {
    float f[8];
    load8f<T>(p, f);
    short8 r;
    #pragma unroll
    for (int j = 0; j < 8; ++j) r[j] = (short)f2bu(f[j] * s);
    return r;
}

// ---- runtime dtype probe (proven) -----------------------------------------
__global__ void detect_dtype_kernel(const unsigned short* __restrict__ x,
                                    int* __restrict__ flag) {
    __shared__ int cnt;
    if (threadIdx.x == 0) cnt = 0;
    __syncthreads();
    int local = 0;
    for (int i = threadIdx.x; i < 2048; i += 256) {
        float v = bits2f((unsigned int)x[i]);
        if (!(fabsf(v) < 1e4f)) local++;
    }
    atomicAdd(&cnt, local);
    __syncthreads();
    if (threadIdx.x == 0) flag[0] = (cnt >= 8) ? 1 : 0;
}

// ========== MFMA GEMM, BK=64, reg-prefetch, conflict-free LDS ==============
// C = act(A @ Bw^T + bias). 128x128 tile, 4 waves 2x2, wave = 4x4 of 16x16x32.
// LDS rows 72 ushorts = 144 B: 2-way bank aliasing only (free, m136).
template <typename T>
__device__ __forceinline__ void gemm_body(
    const T* __restrict__ A, const T* __restrict__ Bw,
    const T* __restrict__ bias, T* __restrict__ C,
    int N, int K, int bm, int bn, int relu)
{
    __shared__ ushort As[128][72];
    __shared__ ushort Bs[128][72];
    const int tid = threadIdx.x;
    const int w = tid >> 6, lane = tid & 63;
    const int quad = lane >> 4, l15 = lane & 15;
    const int wr = (w >> 1) * 64, wc = (w & 1) * 64;

    const int sr = tid >> 1;
    const int sc = (tid & 1) * 32;

    f32x4 acc[4][4];
    #pragma unroll
    for (int i = 0; i < 4; ++i)
        #pragma unroll
        for (int j = 0; j < 4; ++j) acc[i][j] = (f32x4){0.f, 0.f, 0.f, 0.f};

    const T* aP = A + (size_t)(bm + sr) * K + sc;
    const T* bP = Bw + (size_t)(bn + sr) * K + sc;

    uint4 ra[4], rb[4];
    load16b<T>(aP, ra[0], ra[1]);
    load16b<T>(aP + 16, ra[2], ra[3]);
    load16b<T>(bP, rb[0], rb[1]);
    load16b<T>(bP + 16, rb[2], rb[3]);

    for (int k0 = 0; k0 < K; k0 += 64) {
        __syncthreads();
        *(uint4*)&As[sr][sc]      = ra[0];
        *(uint4*)&As[sr][sc + 8]  = ra[1];
        *(uint4*)&As[sr][sc + 16] = ra[2];
        *(uint4*)&As[sr][sc + 24] = ra[3];
        *(uint4*)&Bs[sr][sc]      = rb[0];
        *(uint4*)&Bs[sr][sc + 8]  = rb[1];
        *(uint4*)&Bs[sr][sc + 16] = rb[2];
        *(uint4*)&Bs[sr][sc + 24] = rb[3];
        __syncthreads();
        if (k0 + 64 < K) {  // prefetch next tile; hides behind 32 MFMAs
            load16b<T>(aP + k0 + 64, ra[0], ra[1]);
            load16b<T>(aP + k0 + 80, ra[2], ra[3]);
            load16b<T>(bP + k0 + 64, rb[0], rb[1]);
            load16b<T>(bP + k0 + 80, rb[2], rb[3]);
        }
        #pragma unroll
        for (int kk = 0; kk < 2; ++kk) {
            short8 af[4], bfv[4];
            #pragma unroll
            for (int i = 0; i < 4; ++i) {
                af[i] = *(const short8*)&As[wr + i * 16 + l15][kk * 32 + quad * 8];
                bfv[i] = *(const short8*)&Bs[wc + i * 16 + l15][kk * 32 + quad * 8];
            }
            #pragma unroll
            for (int i = 0; i < 4; ++i)
                #pragma unroll
                for (int j = 0; j < 4; ++j)
                    acc[i][j] = __builtin_amdgcn_mfma_f32_16x16x32_bf16(
                        af[i], bfv[j], acc[i][j], 0, 0, 0);
        }
    }

    #pragma unroll
    for (int j = 0; j < 4; ++j) {
        int col = bn + wc + j * 16 + l15;
        float bv = toF<T>(bias[col]);
        #pragma unroll
        for (int i = 0; i < 4; ++i) {
            int row0 = bm + wr + i * 16 + quad * 4;
            #pragma unroll
            for (int r = 0; r < 4; ++r) {
                float vv = acc[i][j][r] + bv;
                if (relu) vv = fmaxf(vv, 0.f);
                C[(size_t)(row0 + r) * N + col] = fromF<T>(vv);
            }
        }
    }
}

// XCD-locality swizzle: xcd = bx&7 owns m-tiles [4*xcd, 4*xcd+4) and sweeps
// all n-tiles -> per-XCD working set = 4 A-slabs (784 KB) + B, mostly
// L2-resident. Grid must be nTiles*32 (M=4096 fixed).
template <typename T>
__global__ __launch_bounds__(256) void gemm_mfma(
    const int* __restrict__ dflag, int want,
    const T* __restrict__ A, const T* __restrict__ Bw,
    const T* __restrict__ bias, T* __restrict__ C,
    int N, int K, int relu)
{
    if (dflag[0] != want) return;
    const int bx = blockIdx.x;
    const int xcd = bx & 7, i = bx >> 3;
    const int bm = (xcd * 4 + (i & 3)) * 128;
    const int bn = (i >> 2) * 128;
    gemm_body<T>(A, Bw, bias, C, N, K, bm, bn, relu);
}

// Fused QKV with the same swizzle; n2 in 0..17 selects (mat, n-tile)
template <typename T>
__global__ __launch_bounds__(256) void gemm_qkv(
    const int* __restrict__ dflag, int want, const T* __restrict__ x,
    const T* __restrict__ wq, const T* __restrict__ bq,
    const T* __restrict__ wk, const T* __restrict__ bk,
    const T* __restrict__ wv, const T* __restrict__ bv,
    T* __restrict__ qb, T* __restrict__ kb, T* __restrict__ vb)
{
    if (dflag[0] != want) return;
    const int bx = blockIdx.x;
    const int xcd = bx & 7, i = bx >> 3;
    const int bm = (xcd * 4 + (i & 3)) * 128;
    const int n2 = i >> 2;                 // 0..17
    const int mat = n2 / 6;
    const int bn = (n2 % 6) * 128;
    const T* W = (mat == 0) ? wq : (mat == 1) ? wk : wv;
    const T* Bi = (mat == 0) ? bq : (mat == 1) ? bk : bv;
    T* O = (mat == 0) ? qb : (mat == 1) ? kb : vb;
    gemm_body<T>(x, W, Bi, O, 768, 768, bm, bn, 0);
}

// ============== MFMA flash attention + XCD-locality swizzle =================
// xcd owns 3 (b,h) pairs -> per-XCD K/V working set 1.5 MB (L2-resident).
template <typename T>
__global__ __launch_bounds__(256) void attn_mfma(
    const int* __restrict__ dflag, int want,
    const T* __restrict__ q, const T* __restrict__ k,
    const T* __restrict__ v, const int* __restrict__ mask,
    T* __restrict__ ctx)
{
    if (dflag[0] != want) return;
    const int S = 2048, D = 768;
    __shared__ ushort Ks[64][72];
    __shared__ ushort Vt[64][72];
    __shared__ ushort Ps[4][16][72];
    __shared__ float mk[64];

    const int tid = threadIdx.x;
    const int w = tid >> 6, lane = tid & 63;
    const int quad = lane >> 4, l15 = lane & 15;

    const int bx = blockIdx.x;
    const int xcd = bx & 7, ib = bx >> 3;      // ib in 0..95
    const int bh = xcd * 3 + (ib >> 5);        // 0..23
    const int q0 = (ib & 31) * 64;
    const int b = bh / 12, h = bh % 12;

    const size_t qrow = (size_t)(b * S + q0 + w * 16 + l15) * D + h * 64;
    const short8 aQ0 = frag8s<T>(q + qrow + quad * 8, 0.125f);
    const short8 aQ1 = frag8s<T>(q + qrow + 32 + quad * 8, 0.125f);

    f32x4 o[4];
    float m_run[4], l_run[4];
    #pragma unroll
    for (int i = 0; i < 4; ++i) {
        o[i] = (f32x4){0.f, 0.f, 0.f, 0.f};
        m_run[i] = -3.0e38f;
        l_run[i] = 0.f;
    }

    const int sr = tid >> 2;
    const int sc0 = (tid & 3) * 16;

    for (int k0 = 0; k0 < S; k0 += 64) {
        {
            const size_t krow = (size_t)(b * S + k0 + sr) * D + h * 64 + sc0;
            uint4 ka0, ka1, va0, va1;
            load16b<T>(k + krow, ka0, ka1);
            load16b<T>(v + krow, va0, va1);
            *(uint4*)&Ks[sr][sc0] = ka0;
            *(uint4*)&Ks[sr][sc0 + 8] = ka1;
            alignas(16) ushort tmp[16];
            *(uint4*)tmp = va0;
            *(uint4*)(tmp + 8) = va1;
            #pragma unroll
            for (int i = 0; i < 16; ++i) Vt[sc0 + i][sr] = tmp[i];
            if (tid < 64) mk[tid] = mask[b * S + k0 + tid] ? -1e9f : 0.f;
        }
        __syncthreads();

        float p[4][4];
        {
            float scv[4][4];
            float vmax[4] = {-3e38f, -3e38f, -3e38f, -3e38f};
            #pragma unroll
            for (int s = 0; s < 4; ++s) {
                short8 bk0 = *(const short8*)&Ks[s * 16 + l15][quad * 8];
                short8 bk1 = *(const short8*)&Ks[s * 16 + l15][32 + quad * 8];
                f32x4 c = (f32x4){0.f, 0.f, 0.f, 0.f};
                c = __builtin_amdgcn_mfma_f32_16x16x32_bf16(aQ0, bk0, c, 0, 0, 0);
                c = __builtin_amdgcn_mfma_f32_16x16x32_bf16(aQ1, bk1, c, 0, 0, 0);
                float mbias = mk[s * 16 + l15];
                #pragma unroll
                for (int r = 0; r < 4; ++r) {
                    float val = c[r] + mbias;
                    scv[s][r] = val;
                    vmax[r] = fmaxf(vmax[r], val);
                }
            }
            #pragma unroll
            for (int r = 0; r < 4; ++r) {
                float vm = vmax[r];
                vm = fmaxf(vm, __shfl_xor(vm, 1, 16));
                vm = fmaxf(vm, __shfl_xor(vm, 2, 16));
                vm = fmaxf(vm, __shfl_xor(vm, 4, 16));
                vm = fmaxf(vm, __shfl_xor(vm, 8, 16));
                float mn = fmaxf(m_run[r], vm);
                float alpha = __expf(m_run[r] - mn);
                m_run[r] = mn;
                l_run[r] *= alpha;
                #pragma unroll
                for (int s = 0; s < 4; ++s) o[s][r] *= alpha;
                float rs = 0.f;
                #pragma unroll
                for (int s = 0; s < 4; ++s) {
                    p[s][r] = __expf(scv[s][r] - mn);
                    rs += p[s][r];
                }
                rs += __shfl_xor(rs, 1, 16);
                rs += __shfl_xor(rs, 2, 16);
                rs += __shfl_xor(rs, 4, 16);
                rs += __shfl_xor(rs, 8, 16);
                l_run[r] += rs;
            }
        }
        #pragma unroll
        for (int r = 0; r < 4; ++r)
            #pragma unroll
            for (int s = 0; s < 4; ++s)
                Ps[w][quad * 4 + r][s * 16 + l15] = f2bu(p[s][r]);

        {
            short8 aP0 = *(const short8*)&Ps[w][l15][quad * 8];
            short8 aP1 = *(const short8*)&Ps[w][l15][32 + quad * 8];
            #pragma unroll
            for (int s = 0; s < 4; ++s) {
                short8 bv0 = *(const short8*)&Vt[s * 16 + l15][quad * 8];
                short8 bv1 = *(const short8*)&Vt[s * 16 + l15][32 + quad * 8];
                o[s] = __builtin_amdgcn_mfma_f32_16x16x32_bf16(aP0, bv0, o[s], 0, 0, 0);
                o[s] = __builtin_amdgcn_mfma_f32_16x16x32_bf16(aP1, bv1, o[s], 0, 0, 0);
            }
        }
        __syncthreads();
    }

    const size_t obase = (size_t)(b * S + q0 + w * 16) * D + h * 64;
    #pragma unroll
    for (int r = 0; r < 4; ++r) {
        float inv = 1.f / l_run[r];
        #pragma unroll
        for (int s = 0; s < 4; ++s)
            ctx[obase + (size_t)(quad * 4 + r) * D + s * 16 + l15] =
                fromF<T>(o[s][r] * inv);
    }
}

// ---- residual + LayerNorm (proven) ----------------------------------------
template <typename T>
__global__ __launch_bounds__(256) void ln_res_kernel(
    const int* __restrict__ dflag, int want,
    const T* __restrict__ a, const T* __restrict__ r,
    const T* __restrict__ gamma, const T* __restrict__ beta,
    T* __restrict__ out)
{
    if (dflag[0] != want) return;
    const int D = 768;
    const int row = blockIdx.x;
    const int tid = threadIdx.x;
    __shared__ float red[4];
    const size_t base = (size_t)row * D;

    float x[3];
    #pragma unroll
    for (int i = 0; i < 3; ++i) {
        int d = tid + i * 256;
        x[i] = toF<T>(a[base + d]) + toF<T>(r[base + d]);
    }

    float s = x[0] + x[1] + x[2];
    #pragma unroll
    for (int off = 32; off > 0; off >>= 1) s += __shfl_down(s, off, 64);
    if ((tid & 63) == 0) red[tid >> 6] = s;
    __syncthreads();
    float mean = (red[0] + red[1] + red[2] + red[3]) * (1.f / 768.f);
    __syncthreads();

    float vsum = 0.f;
    #pragma unroll
    for (int i = 0; i < 3; ++i) {
        float dd = x[i] - mean;
        vsum += dd * dd;
    }
    #pragma unroll
    for (int off = 32; off > 0; off >>= 1) vsum += __shfl_down(vsum, off, 64);
    if ((tid & 63) == 0) red[tid >> 6] = vsum;
    __syncthreads();
    float var = (red[0] + red[1] + red[2] + red[3]) * (1.f / 767.f);
    float inv = 1.f / (sqrtf(var) + 1e-6f);

    #pragma unroll
    for (int i = 0; i < 3; ++i) {
        int d = tid + i * 256;
        out[base + d] = fromF<T>(toF<T>(gamma[d]) * (x[i] - mean) * inv + toF<T>(beta[d]));
    }
}

// ---- full pipeline for element type T --------------------------------------
template <typename T>
static void launch_pipeline(void* const* d_in, void* d_out, char* buf,
                            const int* dflag, int want, hipStream_t stream)
{
    const int Bb = 2, S = 2048, D = 768, DFF = 3072;
    const int M = Bb * S;

    const T* x    = (const T*)d_in[0];
    const int* mask = (const int*)d_in[1];
    const T* wq = (const T*)d_in[2];
    const T* bq = (const T*)d_in[3];
    const T* wk = (const T*)d_in[4];
    const T* bk = (const T*)d_in[5];
    const T* wv = (const T*)d_in[6];
    const T* bv = (const T*)d_in[7];
    const T* wo = (const T*)d_in[8];
    const T* bo = (const T*)d_in[9];
    const T* w1 = (const T*)d_in[10];
    const T* b1 = (const T*)d_in[11];
    const T* w2 = (const T*)d_in[12];
    const T* b2 = (const T*)d_in[13];
    const T* g1  = (const T*)d_in[14];
    const T* be1 = (const T*)d_in[15];
    const T* g2  = (const T*)d_in[16];
    const T* be2 = (const T*)d_in[17];

    T* out = (T*)d_out;
    T* ws = (T*)buf;

    const size_t nxd = (size_t)M * D;
    const size_t nff = (size_t)M * DFF;

    T* qb    = ws;
    T* kb    = ws + nxd;
    T* vb    = ws + 2 * nxd;
    T* ctx   = ws + nff;
    T* oproj = ws + nff + nxd;
    T* ln1   = ws + nff + 2 * nxd;
    T* ff1   = ws;     // reuse q/k/v region
    T* ff2   = ctx;    // reuse ctx

    dim3 blk(256);
    gemm_qkv<T><<<dim3(18 * 32), blk, 0, stream>>>(dflag, want, x, wq, bq, wk, bk, wv, bv, qb, kb, vb);
    attn_mfma<T><<<dim3(768), blk, 0, stream>>>(dflag, want, qb, kb, vb, mask, ctx);
    gemm_mfma<T><<<dim3(6 * 32), blk, 0, stream>>>(dflag, want, ctx, wo, bo, oproj, D, D, 0);
    ln_res_kernel<T><<<dim3(M), blk, 0, stream>>>(dflag, want, x, oproj, g1, be1, ln1);
    gemm_mfma<T><<<dim3(24 * 32), blk, 0, stream>>>(dflag, want, ln1, w1, b1, ff1, DFF, D, 1);
    gemm_mfma<T><<<dim3(6 * 32), blk, 0, stream>>>(dflag, want, ff1, w2, b2, ff2, D, DFF, 0);
    ln_res_kernel<T><<<dim3(M), blk, 0, stream>>>(dflag, want, ln1, ff2, g2, be2, out);
}

extern "C" void kernel_launch(void* const* d_in, const int* in_sizes, int n_in,
                              void* d_out, int out_size, void* d_ws, size_t ws_size,
                              hipStream_t stream) {
    char* base = (char*)d_ws;
    int* dflag = (int*)base;
    char* buf = base + 256;

    detect_dtype_kernel<<<dim3(1), dim3(256), 0, stream>>>(
        (const unsigned short*)d_in[0], dflag);

    launch_pipeline<bf16>(d_in, d_out, buf, dflag, 0, stream);
    launch_pipeline<float>(d_in, d_out, buf, dflag, 1, stream);
}